// Round 1
// baseline (975.882 us; speedup 1.0000x reference)
//
#include <hip/hip_runtime.h>

// Depthwise conv2d 31x31, pad 15, stride 1, fp32.
// x: (32, 384, 56, 56), weight: (384, 1, 31, 31), bias: (384,)
// Strategy: one block per (n,c) plane. Stage zero-padded 86x86 input tile in
// LDS. Each thread owns one w column x 14-row output strip; per kw it loads a
// 44-tall x column into registers once and does 31x14 FMAs against scalar
// (wave-uniform) weights -> ~10 FMA per LDS read, VALU-bound as intended.

#define DIMC 384
#define HW 56
#define KS 31
#define PADK 15
#define TILE 86          // 56 + 2*15
#define LDS_STRIDE 88    // pad leading dim; 88 % 32 = 24 banks offset per row
#define RH 14            // output rows per thread
#define XR (RH + KS - 1) // 44 register-cached x values

__global__ __launch_bounds__(256, 4)
void dwconv31_kernel(const float* __restrict__ x,
                     const float* __restrict__ w,
                     const float* __restrict__ bias,
                     float* __restrict__ out)
{
    __shared__ float tile[TILE * LDS_STRIDE];

    const int plane = blockIdx.x;          // n*384 + c
    const int c = plane % DIMC;
    const float* __restrict__ xp = x + (size_t)plane * (HW * HW);
    const float* __restrict__ wp = w + (size_t)c * (KS * KS);
    const int tid = threadIdx.x;

    // ---- stage input tile (zero-padded) into LDS ----
    for (int idx = tid; idx < TILE * TILE; idx += 256) {
        int r  = idx / TILE;
        int cc = idx - r * TILE;
        int gr = r - PADK;
        int gc = cc - PADK;
        float v = 0.0f;
        if ((unsigned)gr < (unsigned)HW && (unsigned)gc < (unsigned)HW)
            v = xp[gr * HW + gc];
        tile[r * LDS_STRIDE + cc] = v;
    }
    __syncthreads();

    // ---- compute ----
    const int tx = tid & 63;               // w column (active if < 56)
    const int h0 = (tid >> 6) * RH;        // output rows h0 .. h0+13

    float acc[RH];
#pragma unroll
    for (int j = 0; j < RH; ++j) acc[j] = 0.0f;

    if (tx < HW) {
#pragma unroll 1
        for (int kw = 0; kw < KS; ++kw) {
            // register-cache the x column for this kw: lds rows h0 .. h0+43
            float xr[XR];
#pragma unroll
            for (int i = 0; i < XR; ++i)
                xr[i] = tile[(h0 + i) * LDS_STRIDE + tx + kw];

#pragma unroll
            for (int kh = 0; kh < KS; ++kh) {
                float wv = wp[kh * KS + kw];   // wave-uniform -> s_load / K$
#pragma unroll
                for (int j = 0; j < RH; ++j)
                    acc[j] = fmaf(xr[j + kh], wv, acc[j]);
            }
        }

        const float b = bias[c];
        float* __restrict__ op = out + (size_t)plane * (HW * HW);
#pragma unroll
        for (int j = 0; j < RH; ++j)
            op[(h0 + j) * HW + tx] = acc[j] + b;
    }
}

extern "C" void kernel_launch(void* const* d_in, const int* in_sizes, int n_in,
                              void* d_out, int out_size, void* d_ws, size_t ws_size,
                              hipStream_t stream) {
    const float* x    = (const float*)d_in[0];
    const float* wgt  = (const float*)d_in[1];
    const float* bias = (const float*)d_in[2];
    float* out = (float*)d_out;

    const int nplanes = 32 * DIMC;  // 12288 blocks, one per (n,c) plane
    dwconv31_kernel<<<nplanes, 256, 0, stream>>>(x, wgt, bias, out);
}

// Round 2
// 913.704 us; speedup vs baseline: 1.0681x; 1.0681x over previous
//
#include <hip/hip_runtime.h>

// Depthwise conv2d 31x31, pad 15, stride 1. fp32 in/out, fp16 dot2 inner.
// v_dot2_f32_f16: 2 MACs/instr at full VALU rate, fp32 accumulator ->
// 2x the fp32 FMA throughput. Taps paired along kw; packed (c,c+1) LDS
// reads; dual shifted tile copies fix 4B alignment for odd columns.

#define DIMC 384
#define HW 56
#define KS 31
#define PADK 15
#define TROWS 86
#define TCOLS 88          // 86 cols + zero pad to keep pair reads in range
#define RH 14             // output rows per thread
#define NP 16             // kw pairs (31 -> 16, last padded with w=0)

typedef _Float16 half2v __attribute__((ext_vector_type(2)));

__device__ __forceinline__ float dot2f(half2v a, half2v b, float c) {
#if defined(__has_builtin) && __has_builtin(__builtin_amdgcn_fdot2)
    return __builtin_amdgcn_fdot2(a, b, c, false);
#else
    return fmaf((float)a.x, (float)b.x, fmaf((float)a.y, (float)b.y, c));
#endif
}

__global__ __launch_bounds__(256, 4)
void dwconv31_dot2(const float* __restrict__ x,
                   const float* __restrict__ w,
                   const float* __restrict__ bias,
                   float* __restrict__ out)
{
    // t0: padded tile cols 0..87 (86,87 = zero). t1[r][j] = t0[r][j+1].
    __shared__ _Float16 t0[TROWS * TCOLS];
    __shared__ _Float16 t1[TROWS * TCOLS];
    __shared__ half2v  wlds[KS * NP];   // fp16 weight pairs (kw 2p, 2p+1)

    const int plane = blockIdx.x;              // n*384 + c
    const int c = plane % DIMC;
    const float* __restrict__ xp = x + (size_t)plane * (HW * HW);
    const float* __restrict__ wp = w + (size_t)c * (KS * KS);
    const int tid = threadIdx.x;

    // ---- stage packed fp16 weight pairs ----
    for (int i = tid; i < KS * NP; i += 256) {
        int kh = i / NP, p = i - kh * NP;
        float a = wp[kh * KS + 2 * p];
        float b = (2 * p + 1 < KS) ? wp[kh * KS + 2 * p + 1] : 0.0f;
        half2v hv;
        hv.x = (_Float16)a;
        hv.y = (_Float16)b;
        wlds[i] = hv;
    }

    // ---- stage input tile (zero-padded), two shifted copies ----
    for (int idx = tid; idx < TROWS * TCOLS; idx += 256) {
        int r  = idx / TCOLS;
        int cc = idx - r * TCOLS;
        int gr = r - PADK;
        int gc = cc - PADK;
        float v = 0.0f;
        if ((unsigned)gr < (unsigned)HW && (unsigned)gc < (unsigned)HW)
            v = xp[gr * HW + gc];
        _Float16 hv = (_Float16)v;
        t0[r * TCOLS + cc] = hv;
        if (cc >= 1) t1[r * TCOLS + cc - 1] = hv;
        else         t1[r * TCOLS + TCOLS - 1] = (_Float16)0.0f; // hygiene
    }
    __syncthreads();

    // ---- compute ----
    const int tx = tid & 63;              // w column (active if < 56)
    const int h0 = (tid >> 6) * RH;       // output rows h0 .. h0+13

    float acc[RH];
#pragma unroll
    for (int j = 0; j < RH; ++j) acc[j] = 0.0f;

    if (tx < HW) {
        // 4B-aligned packed base: even tx -> t0 at col tx, odd -> t1 at col tx-1
        const _Float16* base = (tx & 1) ? (t1 + (tx - 1)) : (t0 + tx);

#pragma unroll 1
        for (int p = 0; p < NP; ++p) {
            const _Float16* colp = base + 2 * p;
#pragma unroll 1
            for (int khc = 0; khc < 2; ++khc) {
                const int kh0 = khc * 16;
                const int nkh = khc ? 15 : 16;   // kh 0..15, 16..30

                // register-cache 29 packed rows: h0+kh0 .. h0+kh0+28
                half2v xr[29];
#pragma unroll
                for (int i = 0; i < 29; ++i)
                    xr[i] = *(const half2v*)(colp + (h0 + kh0 + i) * TCOLS);

#pragma unroll
                for (int kk = 0; kk < 16; ++kk) {
                    if (kk < nkh) {
                        half2v wv = wlds[(kh0 + kk) * NP + p];
#pragma unroll
                        for (int j = 0; j < RH; ++j)
                            acc[j] = dot2f(xr[kk + j], wv, acc[j]);
                    }
                }
            }
        }

        const float b = bias[c];
        float* __restrict__ op = out + (size_t)plane * (HW * HW);
#pragma unroll
        for (int j = 0; j < RH; ++j)
            op[(h0 + j) * HW + tx] = acc[j] + b;
    }
}

extern "C" void kernel_launch(void* const* d_in, const int* in_sizes, int n_in,
                              void* d_out, int out_size, void* d_ws, size_t ws_size,
                              hipStream_t stream) {
    const float* x    = (const float*)d_in[0];
    const float* wgt  = (const float*)d_in[1];
    const float* bias = (const float*)d_in[2];
    float* out = (float*)d_out;

    const int nplanes = 32 * DIMC;  // one block per (n,c) plane
    dwconv31_dot2<<<nplanes, 256, 0, stream>>>(x, wgt, bias, out);
}